// Round 5
// baseline (392.201 us; speedup 1.0000x reference)
//
#include <hip/hip_runtime.h>

// MoE fused forward: out = (relu(x@W1[e]+b1[e])@W2[e]+b2[e]) * exp(min(T, log100))
// N=524288, D=128, H=512, E=8, contiguous expert chunks.
// R5: producer/consumer wave specialization. 512 blocks x 1024 threads (16 waves,
// 4/SIMD -- requires VGPR<=128, enforced by disjoint role branches sharing
// physical regs). Waves 0-7: GEMM1 (xb + bias in regs, w1s LDS-resident 128KB).
// Waves 8-15: GEMM2 (w2 in 64 VGPRs, acc2, stores). hsb double-buffered 8KB;
// per interval: GEMM1(c) || GEMM2(c-1), one lgkm-only barrier. No counted vmcnt.

#define CLAMP_MAXV 4.605170185988091f

typedef __attribute__((ext_vector_type(8))) short s16x8;
typedef __attribute__((ext_vector_type(4))) float f32x4;
typedef __attribute__((ext_vector_type(4))) unsigned short u16x4;
typedef __attribute__((ext_vector_type(8))) unsigned short u16x8;

static __device__ __forceinline__ unsigned short f2bf(float f) {
  union { float f; unsigned int u; } v; v.f = f;
  unsigned int r = v.u + 0x7FFFu + ((v.u >> 16) & 1u);  // RNE
  return (unsigned short)(r >> 16);
}

static __device__ __forceinline__ void gll16(const void* src, void* dst) {
  __builtin_amdgcn_global_load_lds((const __attribute__((address_space(1))) void*)src,
                                   (__attribute__((address_space(3))) void*)dst, 16, 0, 0);
}

// LDS-only barrier: own-wave lgkm drain + s_barrier (vmcnt NOT drained; the only
// in-flight VMEM are reg-prefetch loads, waited by compiler before use).
#define LBAR() do { \
  asm volatile("s_waitcnt lgkmcnt(0)" ::: "memory"); \
  __builtin_amdgcn_s_barrier(); \
  __builtin_amdgcn_sched_barrier(0); \
} while (0)

// ---- pre-kernel: W1[e][d][h] -> w1t[e][h][d] bf16 ; W2[e][h][d] -> w2t[e][d][h] bf16
__global__ void conv_w(const float* __restrict__ W1, const float* __restrict__ W2,
                       unsigned short* __restrict__ w1t, unsigned short* __restrict__ w2t) {
  int idx = blockIdx.x * 256 + threadIdx.x;  // 131072 total
  if (idx < 65536) {
    int h  = idx & 511;
    int d0 = ((idx >> 9) & 15) << 3;
    int e  = idx >> 13;
    const float* src = W1 + ((size_t)e << 16);
    u16x8 v;
#pragma unroll
    for (int j = 0; j < 8; ++j) v[j] = f2bf(src[(size_t)(d0 + j) * 512 + h]);
    *(u16x8*)(w1t + ((((size_t)e << 9) + h) << 7) + d0) = v;
  } else {
    int i2 = idx - 65536;
    int d  = i2 & 127;
    int h0 = ((i2 >> 7) & 63) << 3;
    int e  = i2 >> 13;
    const float* src = W2 + ((size_t)e << 16);
    u16x8 v;
#pragma unroll
    for (int j = 0; j < 8; ++j) v[j] = f2bf(src[(size_t)(h0 + j) * 128 + d]);
    *(u16x8*)(w2t + ((((size_t)e << 7) + d) << 9) + h0) = v;
  }
}

// ---- fused MoE kernel (wave-specialized producer/consumer)
__global__ __launch_bounds__(1024, 4) void moe_fused(
    const float* __restrict__ x,
    const float* __restrict__ b1,
    const float* __restrict__ b2,
    const float* __restrict__ temp,
    const unsigned short* __restrict__ w1t,
    const unsigned short* __restrict__ w2t,
    float* __restrict__ out)
{
  __shared__ __align__(16) char smem[147456];
  char* const w1s  = smem;            // 128 KB [512 h][128 d] bf16, swz ^((h&7)<<4)
  char* const hsb0 = smem + 131072;   //   8 KB [64 tok][64 h] bf16, swz ^((tok&7)<<4)
  char* const hsb1 = smem + 139264;   //   8 KB
  char* const xs   = smem + 131072;   //  16 KB [64 tok][128 d] bf16 (aliases hsb0+hsb1)

  const int tid  = threadIdx.x;
  const int lane = tid & 63;
  const int wid  = tid >> 6;          // 0..15
  const int l15  = lane & 15;
  const int lg   = lane >> 4;
  const int blk  = blockIdx.x;
  const int e    = blk >> 6;          // 64 blocks per expert
  const size_t tok0 = (size_t)blk << 10;   // 1024 tokens per block

  const unsigned short* w1g = w1t + ((size_t)e << 16);
  const unsigned short* w2g = w2t + ((size_t)e << 16);
  const float* xblk = x + (tok0 << 7);
  float* const oblk = out + (tok0 << 7);

  // ---- prologue: stage w1 (128 KB) once per block, source pre-swizzled
#pragma unroll
  for (int k = 0; k < 8; ++k) {
    int s = tid + (k << 10);          // 0..8191 slots of 16 B
    int h = s >> 4, sr = s & 15;
    gll16(w1g + ((size_t)h << 7) + ((sr ^ (h & 7)) << 3), w1s + (s << 4));
  }

  // x tile 0 into regs (each thread owns 8 floats = 1 row-slice of 8 d)
  f32x4 xv[2];
  xv[0] = *(const f32x4*)(xblk + (tid << 3));
  xv[1] = *(const f32x4*)(xblk + (tid << 3) + 4);

  __syncthreads();  // full drain: w1s landed

  // xs-write address (same thread-mapping both roles): tok = tid>>4, col = (tid&15)*8
  const int xtok = tid >> 4;
  const unsigned xaddr = (unsigned)((xtok << 8) + ((tid & 15) << 4)) ^ (unsigned)((xtok & 7) << 4);

  if (wid < 8) {
    // ================= PRODUCER: GEMM1 =================
    const int hr  = wid & 3;
    const int tq0 = (wid >> 2) << 5;
    const unsigned hl2 = (unsigned)(((hr << 4) + (lg << 2)) << 1);

    // bias regs: 8 chunks x 4 consecutive h
    f32x4 bias[8];
    const float* b1e = b1 + (e << 9);
#pragma unroll
    for (int c = 0; c < 8; ++c)
      bias[c] = *(const f32x4*)(b1e + (c << 6) + (hr << 4) + (lg << 2));

#pragma unroll 1
    for (int t = 0; t < 16; ++t) {
      // write xs
      u16x8 p;
#pragma unroll
      for (int i = 0; i < 8; ++i) p[i] = f2bf(xv[i >> 2][i & 3]);
      *(u16x8*)(xs + xaddr) = p;
      LBAR();

      // hoist x fragments (wave's 32-token half)
      s16x8 xb[2][4];
#pragma unroll
      for (int j = 0; j < 2; ++j) {
        int tk = tq0 + (j << 4) + l15;
#pragma unroll
        for (int ks = 0; ks < 4; ++ks) {
          unsigned koff = (unsigned)((ks << 6) + (lg << 4));
          xb[j][ks] = *(const s16x8*)(xs + (((unsigned)(tk << 8) + koff) ^ (unsigned)((tk & 7) << 4)));
        }
      }
      LBAR();

#pragma unroll 1
      for (int c = 0; c <= 8; ++c) {
        if (c < 8) {
          const int hrow = (c << 6) + (hr << 4) + l15;
          const unsigned hswz = (unsigned)((hrow & 7) << 4);
          s16x8 a[4];
#pragma unroll
          for (int ks = 0; ks < 4; ++ks) {
            unsigned koff = (unsigned)((ks << 6) + (lg << 4));
            a[ks] = *(const s16x8*)(w1s + (((unsigned)(hrow << 8) + koff) ^ hswz));
          }
          f32x4 acc1[2];
          acc1[0] = (f32x4){0.f, 0.f, 0.f, 0.f};
          acc1[1] = (f32x4){0.f, 0.f, 0.f, 0.f};
#pragma unroll
          for (int j = 0; j < 2; ++j)
#pragma unroll
            for (int ks = 0; ks < 4; ++ks)
              acc1[j] = __builtin_amdgcn_mfma_f32_16x16x32_bf16(a[ks], xb[j][ks], acc1[j], 0, 0, 0);

          char* const hw = (c & 1) ? hsb1 : hsb0;
#pragma unroll
          for (int j = 0; j < 2; ++j) {
            int tk = tq0 + (j << 4) + l15;
            u16x4 q;
#pragma unroll
            for (int r = 0; r < 4; ++r)
              q[r] = f2bf(fmaxf(acc1[j][r] + bias[c][r], 0.f));
            *(u16x4*)(hw + (((unsigned)(tk << 7) + hl2) ^ (unsigned)((tk & 7) << 4))) = q;
          }
        }
        if (c == 4 && t < 15) {
          const float* xn = xblk + (((size_t)t + 1) << 13);
          xv[0] = *(const f32x4*)(xn + (tid << 3));
          xv[1] = *(const f32x4*)(xn + (tid << 3) + 4);
        }
        LBAR();
      }
    }
  } else {
    // ================= CONSUMER: GEMM2 + store =================
    const int cw = wid - 8;
    const int dlane = (cw << 4) + l15;

    // w2 fragments: wave owns d-slice [cw*16, cw*16+16), all 512 h (64 VGPR)
    s16x8 w2f[8][2];
#pragma unroll
    for (int c = 0; c < 8; ++c)
#pragma unroll
      for (int ks = 0; ks < 2; ++ks)
        w2f[c][ks] = *(const s16x8*)(w2g + ((size_t)dlane << 9) + (c << 6) + (ks << 5) + (lg << 3));

    const float b2v   = b2[(e << 7) + dlane];
    const float scale = expf(fminf(temp[0], CLAMP_MAXV));

#pragma unroll 1
    for (int t = 0; t < 16; ++t) {
      // write xs (same mapping as producers)
      u16x8 p;
#pragma unroll
      for (int i = 0; i < 8; ++i) p[i] = f2bf(xv[i >> 2][i & 3]);
      *(u16x8*)(xs + xaddr) = p;
      LBAR();
      // (producers hoist here)
      LBAR();

      f32x4 acc2[4];
#pragma unroll
      for (int i = 0; i < 4; ++i) acc2[i] = (f32x4){0.f, 0.f, 0.f, 0.f};

#pragma unroll 1
      for (int c = 0; c <= 8; ++c) {
        if (c >= 1) {
          const int cc = c - 1;
          char* const hrd = (cc & 1) ? hsb1 : hsb0;
#pragma unroll
          for (int i = 0; i < 4; ++i) {
            int tk = (i << 4) + l15;
            unsigned tswz = (unsigned)((tk & 7) << 4);
#pragma unroll
            for (int ks = 0; ks < 2; ++ks) {
              unsigned koff = (unsigned)((ks << 6) + (lg << 4));
              s16x8 ha = *(const s16x8*)(hrd + (((unsigned)(tk << 7) + koff) ^ tswz));
              acc2[i] = __builtin_amdgcn_mfma_f32_16x16x32_bf16(ha, w2f[cc][ks], acc2[i], 0, 0, 0);
            }
          }
        }
        if (c == 4 && t < 15) {
          const float* xn = xblk + (((size_t)t + 1) << 13);
          xv[0] = *(const f32x4*)(xn + (tid << 3));
          xv[1] = *(const f32x4*)(xn + (tid << 3) + 4);
        }
        LBAR();
      }

      // store tile t: wave covers all 64 tok x its 16 d
      float* og = oblk + ((size_t)t << 13);
#pragma unroll
      for (int i = 0; i < 4; ++i) {
#pragma unroll
        for (int r = 0; r < 4; ++r) {
          int tk = (i << 4) + (lg << 2) + r;
          og[((size_t)tk << 7) + dlane] = (acc2[i][r] + b2v) * scale;
        }
      }
    }
  }
}

// ---- fallback (only if ws_size is tiny): naive but correct
__global__ void moe_naive(const float* __restrict__ x, const float* __restrict__ W1,
                          const float* __restrict__ b1, const float* __restrict__ W2,
                          const float* __restrict__ b2, const float* __restrict__ temp,
                          float* __restrict__ out) {
  __shared__ float xr[128];
  __shared__ float hrow[512];
  int t = blockIdx.x;
  int e = t >> 16;
  int tx = threadIdx.x;
  xr[tx] = x[((size_t)t << 7) + tx];
  __syncthreads();
  const float* w1e = W1 + ((size_t)e << 16);
  for (int h = tx; h < 512; h += 128) {
    float s = b1[(e << 9) + h];
    for (int d = 0; d < 128; ++d) s += xr[d] * w1e[(size_t)d * 512 + h];
    hrow[h] = fmaxf(s, 0.f);
  }
  __syncthreads();
  const float* w2e = W2 + ((size_t)e << 16);
  float s = b2[(e << 7) + tx];
  for (int h = 0; h < 512; ++h) s += hrow[h] * w2e[(size_t)h * 128 + tx];
  out[((size_t)t << 7) + tx] = s * expf(fminf(temp[0], CLAMP_MAXV));
}

extern "C" void kernel_launch(void* const* d_in, const int* in_sizes, int n_in,
                              void* d_out, int out_size, void* d_ws, size_t ws_size,
                              hipStream_t stream) {
  const float* x    = (const float*)d_in[0];
  const float* W1   = (const float*)d_in[1];
  const float* b1   = (const float*)d_in[2];
  const float* W2   = (const float*)d_in[3];
  const float* b2   = (const float*)d_in[4];
  const float* temp = (const float*)d_in[5];
  float* out = (float*)d_out;

  const size_t WS_NEEDED = 2u * 524288u * sizeof(unsigned short);  // 2 MB
  if (ws_size >= WS_NEEDED) {
    unsigned short* w1t = (unsigned short*)d_ws;
    unsigned short* w2t = w1t + 524288;
    conv_w<<<512, 256, 0, stream>>>(W1, W2, w1t, w2t);
    moe_fused<<<512, 1024, 0, stream>>>(x, b1, b2, temp, w1t, w2t, out);
  } else {
    moe_naive<<<524288, 128, 0, stream>>>(x, W1, b1, W2, b2, temp, out);
  }
}

// Round 6
// 178.250 us; speedup vs baseline: 2.2003x; 2.2003x over previous
//
#include <hip/hip_runtime.h>

// MoE fused forward: out = (relu(x@W1[e]+b1[e])@W2[e]+b2[e]) * exp(min(T, log100))
// N=524288, D=128, H=512, E=8, contiguous expert chunks.
// R6: R5's producer/consumer wave specialization (512 blocks x 1024 thr, 16
// waves = 4/SIMD) with the rule-#20 fix: chunk loops FULLY UNROLLED so
// w2f[][]/hsb/bias indices are compile-time constants (R5's `unroll 1` sent
// w2f+bias to scratch: VGPR=52, FETCH 925MB, 2x slowdown). b1 bias in LDS to
// keep producer regs low. Waves 0-7: GEMM1 (w1s LDS 128KB). Waves 8-15: GEMM2
// (w2 in 64 VGPRs) + stores. hsb dbuf 8KB; one lgkm-only barrier per interval.

#define CLAMP_MAXV 4.605170185988091f

typedef __attribute__((ext_vector_type(8))) short s16x8;
typedef __attribute__((ext_vector_type(4))) float f32x4;
typedef __attribute__((ext_vector_type(4))) unsigned short u16x4;
typedef __attribute__((ext_vector_type(8))) unsigned short u16x8;

static __device__ __forceinline__ unsigned short f2bf(float f) {
  union { float f; unsigned int u; } v; v.f = f;
  unsigned int r = v.u + 0x7FFFu + ((v.u >> 16) & 1u);  // RNE
  return (unsigned short)(r >> 16);
}

static __device__ __forceinline__ void gll16(const void* src, void* dst) {
  __builtin_amdgcn_global_load_lds((const __attribute__((address_space(1))) void*)src,
                                   (__attribute__((address_space(3))) void*)dst, 16, 0, 0);
}

// LDS-only barrier: own-wave lgkm drain + s_barrier (vmcnt NOT drained; the only
// in-flight VMEM are reg-prefetch loads, waited by compiler before use).
#define LBAR() do { \
  asm volatile("s_waitcnt lgkmcnt(0)" ::: "memory"); \
  __builtin_amdgcn_s_barrier(); \
  __builtin_amdgcn_sched_barrier(0); \
} while (0)

// ---- pre-kernel: W1[e][d][h] -> w1t[e][h][d] bf16 ; W2[e][h][d] -> w2t[e][d][h] bf16
__global__ void conv_w(const float* __restrict__ W1, const float* __restrict__ W2,
                       unsigned short* __restrict__ w1t, unsigned short* __restrict__ w2t) {
  int idx = blockIdx.x * 256 + threadIdx.x;  // 131072 total
  if (idx < 65536) {
    int h  = idx & 511;
    int d0 = ((idx >> 9) & 15) << 3;
    int e  = idx >> 13;
    const float* src = W1 + ((size_t)e << 16);
    u16x8 v;
#pragma unroll
    for (int j = 0; j < 8; ++j) v[j] = f2bf(src[(size_t)(d0 + j) * 512 + h]);
    *(u16x8*)(w1t + ((((size_t)e << 9) + h) << 7) + d0) = v;
  } else {
    int i2 = idx - 65536;
    int d  = i2 & 127;
    int h0 = ((i2 >> 7) & 63) << 3;
    int e  = i2 >> 13;
    const float* src = W2 + ((size_t)e << 16);
    u16x8 v;
#pragma unroll
    for (int j = 0; j < 8; ++j) v[j] = f2bf(src[(size_t)(h0 + j) * 128 + d]);
    *(u16x8*)(w2t + ((((size_t)e << 7) + d) << 9) + h0) = v;
  }
}

// ---- fused MoE kernel (wave-specialized producer/consumer)
__global__ __launch_bounds__(1024, 4) void moe_fused(
    const float* __restrict__ x,
    const float* __restrict__ b1,
    const float* __restrict__ b2,
    const float* __restrict__ temp,
    const unsigned short* __restrict__ w1t,
    const unsigned short* __restrict__ w2t,
    float* __restrict__ out)
{
  __shared__ __align__(16) char smem[149504];
  char* const w1s  = smem;            // 128 KB [512 h][128 d] bf16, swz ^((h&7)<<4)
  char* const hsb0 = smem + 131072;   //   8 KB [64 tok][64 h] bf16, swz ^((tok&7)<<4)
  char* const hsb1 = smem + 139264;   //   8 KB
  char* const xs   = smem + 131072;   //  16 KB [64 tok][128 d] bf16 (aliases hsb0+hsb1)
  float* const b1s = (float*)(smem + 147456);  // 2 KB

  const int tid  = threadIdx.x;
  const int lane = tid & 63;
  const int wid  = tid >> 6;          // 0..15
  const int l15  = lane & 15;
  const int lg   = lane >> 4;
  const int blk  = blockIdx.x;
  const int e    = blk >> 6;          // 64 blocks per expert
  const size_t tok0 = (size_t)blk << 10;   // 1024 tokens per block

  const unsigned short* w1g = w1t + ((size_t)e << 16);
  const unsigned short* w2g = w2t + ((size_t)e << 16);
  const float* xblk = x + (tok0 << 7);
  float* const oblk = out + (tok0 << 7);

  // ---- prologue: stage w1 (128 KB) once per block, source pre-swizzled
#pragma unroll
  for (int k = 0; k < 8; ++k) {
    int s = tid + (k << 10);          // 0..8191 slots of 16 B
    int h = s >> 4, sr = s & 15;
    gll16(w1g + ((size_t)h << 7) + ((sr ^ (h & 7)) << 3), w1s + (s << 4));
  }

  if (tid < 512) b1s[tid] = b1[(e << 9) + tid];

  // x tile 0 into regs (each thread owns 8 floats)
  f32x4 xv[2];
  xv[0] = *(const f32x4*)(xblk + (tid << 3));
  xv[1] = *(const f32x4*)(xblk + (tid << 3) + 4);

  __syncthreads();  // full drain: w1s + b1s landed

  // xs-write address: tok = tid>>4, col = (tid&15)*8
  const int xtok = tid >> 4;
  const unsigned xaddr = (unsigned)((xtok << 8) + ((tid & 15) << 4)) ^ (unsigned)((xtok & 7) << 4);

  if (wid < 8) {
    // ================= PRODUCER: GEMM1 =================
    const int hr  = wid & 3;
    const int tq0 = (wid >> 2) << 5;
    const unsigned hl2 = (unsigned)(((hr << 4) + (lg << 2)) << 1);

#pragma unroll 1
    for (int t = 0; t < 16; ++t) {
      // write xs
      u16x8 p;
#pragma unroll
      for (int i = 0; i < 8; ++i) p[i] = f2bf(xv[i >> 2][i & 3]);
      *(u16x8*)(xs + xaddr) = p;
      LBAR();

      // hoist x fragments (wave's 32-token half)
      s16x8 xb[2][4];
#pragma unroll
      for (int j = 0; j < 2; ++j) {
        int tk = tq0 + (j << 4) + l15;
#pragma unroll
        for (int ks = 0; ks < 4; ++ks) {
          unsigned koff = (unsigned)((ks << 6) + (lg << 4));
          xb[j][ks] = *(const s16x8*)(xs + (((unsigned)(tk << 8) + koff) ^ (unsigned)((tk & 7) << 4)));
        }
      }
      LBAR();

#pragma unroll
      for (int c = 0; c <= 8; ++c) {
        if (c < 8) {
          const int hrow = (c << 6) + (hr << 4) + l15;
          const unsigned hswz = (unsigned)((hrow & 7) << 4);
          s16x8 a[4];
#pragma unroll
          for (int ks = 0; ks < 4; ++ks) {
            unsigned koff = (unsigned)((ks << 6) + (lg << 4));
            a[ks] = *(const s16x8*)(w1s + (((unsigned)(hrow << 8) + koff) ^ hswz));
          }
          f32x4 bias = *(const f32x4*)(b1s + (c << 6) + (hr << 4) + (lg << 2));
          f32x4 acc1[2];
          acc1[0] = (f32x4){0.f, 0.f, 0.f, 0.f};
          acc1[1] = (f32x4){0.f, 0.f, 0.f, 0.f};
#pragma unroll
          for (int j = 0; j < 2; ++j)
#pragma unroll
            for (int ks = 0; ks < 4; ++ks)
              acc1[j] = __builtin_amdgcn_mfma_f32_16x16x32_bf16(a[ks], xb[j][ks], acc1[j], 0, 0, 0);

          char* const hw = (c & 1) ? hsb1 : hsb0;
#pragma unroll
          for (int j = 0; j < 2; ++j) {
            int tk = tq0 + (j << 4) + l15;
            u16x4 q;
#pragma unroll
            for (int r = 0; r < 4; ++r)
              q[r] = f2bf(fmaxf(acc1[j][r] + bias[r], 0.f));
            *(u16x4*)(hw + (((unsigned)(tk << 7) + hl2) ^ (unsigned)((tk & 7) << 4))) = q;
          }
        }
        if (c == 4 && t < 15) {
          const float* xn = xblk + (((size_t)t + 1) << 13);
          xv[0] = *(const f32x4*)(xn + (tid << 3));
          xv[1] = *(const f32x4*)(xn + (tid << 3) + 4);
        }
        LBAR();
      }
    }
  } else {
    // ================= CONSUMER: GEMM2 + store =================
    const int cw = wid - 8;
    const int dlane = (cw << 4) + l15;

    // w2 fragments: wave owns d-slice [cw*16, cw*16+16), all 512 h (64 VGPR)
    s16x8 w2f[8][2];
#pragma unroll
    for (int c = 0; c < 8; ++c)
#pragma unroll
      for (int ks = 0; ks < 2; ++ks)
        w2f[c][ks] = *(const s16x8*)(w2g + ((size_t)dlane << 9) + (c << 6) + (ks << 5) + (lg << 3));

    const float b2v   = b2[(e << 7) + dlane];
    const float scale = expf(fminf(temp[0], CLAMP_MAXV));

#pragma unroll 1
    for (int t = 0; t < 16; ++t) {
      // write xs (same mapping as producers)
      u16x8 p;
#pragma unroll
      for (int i = 0; i < 8; ++i) p[i] = f2bf(xv[i >> 2][i & 3]);
      *(u16x8*)(xs + xaddr) = p;
      LBAR();
      // (producers hoist here)
      LBAR();

      f32x4 acc2[4];
#pragma unroll
      for (int i = 0; i < 4; ++i) acc2[i] = (f32x4){0.f, 0.f, 0.f, 0.f};

#pragma unroll
      for (int c = 0; c <= 8; ++c) {
        if (c >= 1) {
          const int cc = c - 1;
          char* const hrd = (cc & 1) ? hsb1 : hsb0;
#pragma unroll
          for (int i = 0; i < 4; ++i) {
            int tk = (i << 4) + l15;
            unsigned tswz = (unsigned)((tk & 7) << 4);
#pragma unroll
            for (int ks = 0; ks < 2; ++ks) {
              unsigned koff = (unsigned)((ks << 6) + (lg << 4));
              s16x8 ha = *(const s16x8*)(hrd + (((unsigned)(tk << 7) + koff) ^ tswz));
              acc2[i] = __builtin_amdgcn_mfma_f32_16x16x32_bf16(ha, w2f[cc][ks], acc2[i], 0, 0, 0);
            }
          }
        }
        if (c == 4 && t < 15) {
          const float* xn = xblk + (((size_t)t + 1) << 13);
          xv[0] = *(const f32x4*)(xn + (tid << 3));
          xv[1] = *(const f32x4*)(xn + (tid << 3) + 4);
        }
        LBAR();
      }

      // store tile t: wave covers all 64 tok x its 16 d
      float* og = oblk + ((size_t)t << 13);
#pragma unroll
      for (int i = 0; i < 4; ++i) {
#pragma unroll
        for (int r = 0; r < 4; ++r) {
          int tk = (i << 4) + (lg << 2) + r;
          og[((size_t)tk << 7) + dlane] = (acc2[i][r] + b2v) * scale;
        }
      }
    }
  }
}

// ---- fallback (only if ws_size is tiny): naive but correct
__global__ void moe_naive(const float* __restrict__ x, const float* __restrict__ W1,
                          const float* __restrict__ b1, const float* __restrict__ W2,
                          const float* __restrict__ b2, const float* __restrict__ temp,
                          float* __restrict__ out) {
  __shared__ float xr[128];
  __shared__ float hrow[512];
  int t = blockIdx.x;
  int e = t >> 16;
  int tx = threadIdx.x;
  xr[tx] = x[((size_t)t << 7) + tx];
  __syncthreads();
  const float* w1e = W1 + ((size_t)e << 16);
  for (int h = tx; h < 512; h += 128) {
    float s = b1[(e << 9) + h];
    for (int d = 0; d < 128; ++d) s += xr[d] * w1e[(size_t)d * 512 + h];
    hrow[h] = fmaxf(s, 0.f);
  }
  __syncthreads();
  const float* w2e = W2 + ((size_t)e << 16);
  float s = b2[(e << 7) + tx];
  for (int h = 0; h < 512; ++h) s += hrow[h] * w2e[(size_t)h * 128 + tx];
  out[((size_t)t << 7) + tx] = s * expf(fminf(temp[0], CLAMP_MAXV));
}

extern "C" void kernel_launch(void* const* d_in, const int* in_sizes, int n_in,
                              void* d_out, int out_size, void* d_ws, size_t ws_size,
                              hipStream_t stream) {
  const float* x    = (const float*)d_in[0];
  const float* W1   = (const float*)d_in[1];
  const float* b1   = (const float*)d_in[2];
  const float* W2   = (const float*)d_in[3];
  const float* b2   = (const float*)d_in[4];
  const float* temp = (const float*)d_in[5];
  float* out = (float*)d_out;

  const size_t WS_NEEDED = 2u * 524288u * sizeof(unsigned short);  // 2 MB
  if (ws_size >= WS_NEEDED) {
    unsigned short* w1t = (unsigned short*)d_ws;
    unsigned short* w2t = w1t + 524288;
    conv_w<<<512, 256, 0, stream>>>(W1, W2, w1t, w2t);
    moe_fused<<<512, 1024, 0, stream>>>(x, b1, b2, temp, w1t, w2t, out);
  } else {
    moe_naive<<<524288, 128, 0, stream>>>(x, W1, b1, W2, b2, temp, out);
  }
}